// Round 1
// 4136.553 us; speedup vs baseline: 1.0497x; 1.0497x over previous
//
#include <hip/hip_runtime.h>
#include <math.h>

#define BSZ   512
#define TSTEPS 16
#define HID   2048
#define G4    8192
#define ZD    512
#define ABF   16384
#define ENCK  6144   // [r(2048) | h_dec(2048) | h_enc(2048)]
#define DECK  2560   // [z(512) | h_dec(2048)]
#define LOG2PI_F 1.8378770664093453f

typedef float  f32x4  __attribute__((ext_vector_type(4)));
typedef __bf16 bf16x8 __attribute__((ext_vector_type(8)));
typedef unsigned short u16;
typedef u16 u16x4 __attribute__((ext_vector_type(4)));
typedef u16 u16x8v __attribute__((ext_vector_type(8)));
union bfcast { u16x8v u; bf16x8 b; };

__device__ __forceinline__ u16 f2bf(float f){
  union { float f; unsigned u; } v; v.f = f;
  unsigned u = v.u;
  return (u16)((u + 0x7FFFu + ((u >> 16) & 1u)) >> 16);   // RNE
}
__device__ __forceinline__ float bf2f(u16 u){
  union { unsigned u; float f; } v; v.u = ((unsigned)u) << 16; return v.f;
}
__device__ __forceinline__ float sigm(float x){ return 1.f/(1.f + expf(-x)); }

__device__ __forceinline__ void load_lds16(const void* g, void* l){
  __builtin_amdgcn_global_load_lds(
      (const __attribute__((address_space(1))) void*)g,
      (__attribute__((address_space(3))) void*)l, 16, 0, 0);
}

__device__ __forceinline__ float wsum(float v){
  #pragma unroll
  for (int o = 32; o; o >>= 1) v += __shfl_down(v, o, 64);
  return v;
}

// ---------------- utility kernels ----------------
__global__ __launch_bounds__(256) void zero_kernel(float* __restrict__ p, int n4){
  int i = blockIdx.x*256 + threadIdx.x;
  const int st = gridDim.x*256;
  f32x4 z = {0.f,0.f,0.f,0.f};
  for (; i < n4; i += st) ((f32x4*)p)[i] = z;
}

__global__ __launch_bounds__(256) void cvt_kernel(const float* __restrict__ s, u16* __restrict__ d, int n4){
  int i = blockIdx.x*256 + threadIdx.x;
  const int st = gridDim.x*256;
  for (; i < n4; i += st){
    f32x4 v = ((const f32x4*)s)[i];
    u16x4 o;
    o[0]=f2bf(v[0]); o[1]=f2bf(v[1]); o[2]=f2bf(v[2]); o[3]=f2bf(v[3]);
    ((u16x4*)d)[i] = o;
  }
}

// f32 [rows x srcC] -> bf16 strided dst (dst row stride dstride elems, col offset coloff)
// sh = log2(srcC/4), cmask = srcC/4 - 1 (srcC power of 2)
__global__ __launch_bounds__(256) void cvt_strided_kernel(
    const float* __restrict__ s, u16* __restrict__ d,
    int n4, int sh, int cmask, int dstride, int coloff)
{
  int i = blockIdx.x*256 + threadIdx.x;
  const int st = gridDim.x*256;
  for (; i < n4; i += st){
    f32x4 v = ((const f32x4*)s)[i];
    u16x4 o;
    o[0]=f2bf(v[0]); o[1]=f2bf(v[1]); o[2]=f2bf(v[2]); o[3]=f2bf(v[3]);
    const int row = i >> sh;
    const int c4  = i & cmask;
    *(u16x4*)&d[(size_t)row*dstride + coloff + c4*4] = o;
  }
}

// ---------------- fused read: attn + xhat + glimpse (MFMA) ----------------
// hd = decA+512 (stride DECK), r_out = encA (stride ENCK, cols 0:2048)
__global__ __launch_bounds__(256) void read_fused(
    const u16* __restrict__ x_bf, const float* __restrict__ canvas,
    const u16* __restrict__ hd, const float* __restrict__ attnW,
    const float* __restrict__ attn_b, u16* __restrict__ r_out)
{
  const int b = blockIdx.x;
  const int tid = threadIdx.x;
  const int wave = tid >> 6;
  const int lane = tid & 63;
  const int lr = lane & 15;
  const int lq = lane >> 4;
  __shared__ float red[4][5];
  __shared__ float prm[5];
  __shared__ float rowsum[32][9];
  __shared__ __align__(16) u16 Fxb[32*128];   // row n, 16B-chunk c stored at c^(n&7)
  __shared__ __align__(16) u16 Fyb[32*128];
  __shared__ __align__(16) u16 Ttx[32*136];   // T[m][B], pad to 136
  __shared__ __align__(16) u16 Ttxh[32*136];

  // ---- attn params ----
  {
    float a0=0,a1=0,a2=0,a3=0,a4=0;
    const u16* h = hd + (size_t)b*DECK;
    for (int k = tid; k < HID; k += 256){
      const float hv = bf2f(h[k]);
      a0 += hv*attnW[k];
      a1 += hv*attnW[HID + k];
      a2 += hv*attnW[2*HID + k];
      a3 += hv*attnW[3*HID + k];
      a4 += hv*attnW[4*HID + k];
    }
    a0 = wsum(a0); a1 = wsum(a1); a2 = wsum(a2); a3 = wsum(a3); a4 = wsum(a4);
    if (lane == 0){
      red[wave][0]=a0; red[wave][1]=a1; red[wave][2]=a2; red[wave][3]=a3; red[wave][4]=a4;
    }
  }
  __syncthreads();
  if (tid < 5){
    const float p = red[0][tid]+red[1][tid]+red[2][tid]+red[3][tid] + attn_b[tid];
    float v;
    if (tid <= 1)      v = 64.5f*(p + 1.f);
    else if (tid == 2) v = 1.f/(2.f*expf(p));       // i2s
    else if (tid == 3) v = (127.f/31.f)*expf(p);    // delta
    else               v = expf(p);                  // gamma
    prm[tid] = v;
  }
  __syncthreads();
  const float gx = prm[0], gy = prm[1], i2s = prm[2], dl = prm[3], gm = prm[4];

  // ---- F generation (bf16, swizzled) ----
  auto genF = [&](float g0, u16* dst){
    const int rr = tid >> 3;
    const int asub = tid & 7;
    const float mu = g0 + ((float)rr - 16.5f)*dl;
    float s = 0.f;
    for (int a = asub*16; a < asub*16 + 16; a++){
      const float t = ((float)a - mu)*i2s;
      s += expf(-t*t);
    }
    rowsum[rr][asub] = s;
    __syncthreads();
    if (tid < 32){
      float tot = 0.f;
      #pragma unroll
      for (int j = 0; j < 8; j++) tot += rowsum[tid][j];
      rowsum[tid][8] = 1.f/(tot + 1e-9f);
    }
    __syncthreads();
    for (int i = tid; i < 4096; i += 256){
      const int n = i >> 7, a = i & 127;
      const float mu2 = g0 + ((float)n - 16.5f)*dl;
      const float t = ((float)a - mu2)*i2s;
      const float v = expf(-t*t)*rowsum[n][8];
      const int pos = (a >> 3) ^ (n & 7);
      dst[n*128 + pos*8 + (a & 7)] = f2bf(v);
    }
    __syncthreads();
  };
  genF(gx, Fxb);
  genF(gy, Fyb);

  // ---- stage 1: T[B][m] = sum_a img[B][a] Fx[m][a], per wave: B-rows [32w,32w+32) ----
  const u16*   xb = x_bf   + (size_t)b*ABF;
  const float* cb = canvas + (size_t)b*ABF;
  f32x4 Cx[2][2], Ch[2][2];
  #pragma unroll
  for (int i = 0; i < 2; i++)
    #pragma unroll
    for (int j = 0; j < 2; j++){ Cx[i][j] = (f32x4){0,0,0,0}; Ch[i][j] = (f32x4){0,0,0,0}; }

  #pragma unroll
  for (int mt = 0; mt < 2; mt++){
    const int row = wave*32 + mt*16 + lr;
    bfcast ax[4], ah[4];
    #pragma unroll
    for (int ks = 0; ks < 4; ks++){
      const int base = row*128 + ks*32 + lq*8;
      ax[ks].u = *(const u16x8v*)&xb[base];
      f32x4 c0 = *(const f32x4*)&cb[base];
      f32x4 c1 = *(const f32x4*)&cb[base + 4];
      #pragma unroll
      for (int j = 0; j < 4; j++){
        ah[ks].u[j]   = f2bf(bf2f(ax[ks].u[j])   - sigm(c0[j]));
        ah[ks].u[4+j] = f2bf(bf2f(ax[ks].u[4+j]) - sigm(c1[j]));
      }
    }
    #pragma unroll
    for (int nt = 0; nt < 2; nt++){
      #pragma unroll
      for (int ks = 0; ks < 4; ks++){
        const int pos = (ks*4 + lq) ^ (lr & 7);
        bf16x8 bf_ = *(const bf16x8*)&Fxb[(nt*16 + lr)*128 + pos*8];
        Cx[mt][nt] = __builtin_amdgcn_mfma_f32_16x16x32_bf16(ax[ks].b, bf_, Cx[mt][nt], 0, 0, 0);
        Ch[mt][nt] = __builtin_amdgcn_mfma_f32_16x16x32_bf16(ah[ks].b, bf_, Ch[mt][nt], 0, 0, 0);
      }
    }
  }
  // write T to LDS as bf16 [m][B] (C-layout: col=lane&15 -> m, row=lq*4+r -> B)
  #pragma unroll
  for (int mt = 0; mt < 2; mt++)
    #pragma unroll
    for (int nt = 0; nt < 2; nt++)
      #pragma unroll
      for (int r = 0; r < 4; r++){
        const int m  = nt*16 + lr;
        const int B_ = wave*32 + mt*16 + lq*4 + r;
        Ttx[m*136 + B_]  = f2bf(Cx[mt][nt][r]);
        Ttxh[m*136 + B_] = f2bf(Ch[mt][nt][r]);
      }
  __syncthreads();

  // ---- stage 2: r[n][m] = sum_B Fy[n][B] T[B][m] ----
  const int mat = wave >> 1;           // 0: x, 1: xhat
  const u16* Tt = mat ? Ttxh : Ttx;
  const int ntl = wave & 1;            // n-half
  f32x4 R[2];
  R[0] = (f32x4){0,0,0,0}; R[1] = (f32x4){0,0,0,0};
  #pragma unroll
  for (int ks = 0; ks < 4; ks++){
    const int pos = (ks*4 + lq) ^ (lr & 7);
    bf16x8 af = *(const bf16x8*)&Fyb[(ntl*16 + lr)*128 + pos*8];
    #pragma unroll
    for (int mt = 0; mt < 2; mt++){
      bf16x8 bf_ = *(const bf16x8*)&Tt[(mt*16 + lr)*136 + ks*32 + lq*8];
      R[mt] = __builtin_amdgcn_mfma_f32_16x16x32_bf16(af, bf_, R[mt], 0, 0, 0);
    }
  }
  #pragma unroll
  for (int mt = 0; mt < 2; mt++){
    const int m = mt*16 + lr;
    #pragma unroll
    for (int r = 0; r < 4; r++){
      const int n = ntl*16 + lq*4 + r;
      r_out[(size_t)b*ENCK + mat*1024 + n*32 + m] = f2bf(R[mt][r]*gm);
    }
  }
}

// ---------------- bf16 B^T GEMM structs ----------------
struct Slice { const u16* A; const u16* W; const u16* Whi; float* C; int lda, ldw, K, pad; };
struct Slices { Slice s[4]; };

// ---------------- small-tile GEMM (ms / w), unchanged structure ----------------
template<int BM, int BN>
__global__ __launch_bounds__(256) void gemm_bt(Slices sl, int nsplit, int ldc)
{
  constexpr int BK = 64;
  constexpr int FI = BM/32;
  constexpr int FJ = BN/32;
  __shared__ __align__(16) u16 Asm[BM*BK];
  __shared__ __align__(16) u16 Bsm[BN*BK];
  const int tid  = threadIdx.x;
  const int wave = tid >> 6;
  const int lane = tid & 63;
  const int wm = wave & 1, wn = wave >> 1;
  const int m0 = blockIdx.y * BM;
  const int n0 = blockIdx.x * BN;
  const Slice& sp = sl.s[blockIdx.z];
  const u16* Ap = sp.A;
  const u16* Wp = sp.W;
  const int lda = sp.lda, ldw = sp.ldw, K = sp.K;
  if (nsplit > 0 && n0 >= nsplit) Wp = sp.Whi - (size_t)nsplit * ldw;
  float* C = sp.C;

  f32x4 acc[FI][FJ];
  #pragma unroll
  for (int i = 0; i < FI; i++)
    #pragma unroll
    for (int j = 0; j < FJ; j++) acc[i][j] = (f32x4){0.f,0.f,0.f,0.f};

  const int lr = lane & 15;
  const int lq = lane >> 4;

  for (int kt = 0; kt < K; kt += BK){
    __syncthreads();
    constexpr int NCA = BM*BK/8;
    #pragma unroll
    for (int it = 0; it < NCA/256; it++){
      const int cb = it*256 + wave*64;
      const int c  = cb + lane;
      const int row = c >> 3;
      const int c8  = (c & 7) ^ (row & 7);
      load_lds16(Ap + (size_t)(m0 + row)*lda + kt + c8*8, &Asm[cb*8]);
    }
    constexpr int NCB = BN*BK/8;
    #pragma unroll
    for (int it = 0; it < NCB/256; it++){
      const int cb = it*256 + wave*64;
      const int c  = cb + lane;
      const int row = c >> 3;
      const int c8  = (c & 7) ^ (row & 7);
      load_lds16(Wp + (size_t)(n0 + row)*ldw + kt + c8*8, &Bsm[cb*8]);
    }
    __syncthreads();
    #pragma unroll
    for (int ks = 0; ks < 2; ks++){
      bf16x8 af[FI], bfr[FJ];
      #pragma unroll
      for (int i = 0; i < FI; i++){
        const int row = wm*(BM/2) + i*16 + lr;
        const int xx = (ks*4 + lq) ^ (row & 7);
        af[i] = *(const bf16x8*)&Asm[row*BK + xx*8];
      }
      #pragma unroll
      for (int j = 0; j < FJ; j++){
        const int row = wn*(BN/2) + j*16 + lr;
        const int xx = (ks*4 + lq) ^ (row & 7);
        bfr[j] = *(const bf16x8*)&Bsm[row*BK + xx*8];
      }
      #pragma unroll
      for (int i = 0; i < FI; i++)
        #pragma unroll
        for (int j = 0; j < FJ; j++)
          acc[i][j] = __builtin_amdgcn_mfma_f32_16x16x32_bf16(af[i], bfr[j], acc[i][j], 0, 0, 0);
    }
  }
  #pragma unroll
  for (int i = 0; i < FI; i++){
    const int gm = m0 + wm*(BM/2) + i*16 + lq*4;
    #pragma unroll
    for (int j = 0; j < FJ; j++){
      const int gn = n0 + wn*(BN/2) + j*16 + lr;
      #pragma unroll
      for (int r = 0; r < 4; r++)
        C[(size_t)(gm + r)*ldc + gn] = acc[i][j][r];
    }
  }
}

// ---------------- big GEMM: 256x256x64, 8 waves, double-buffered, counted vmcnt ----------------
// grid = 32 (n) x 2 (m) x 4 (split-K) = 256 blocks = 1 block/CU. LDS 128 KiB.
// T2: XOR-swizzled LDS (same chunk math as gemm_bt). T3/T4: loads for tile t+1
// stay in flight across tile t's compute; single vmcnt(8) per K-tile, never 0
// in the main loop. T5: setprio around MFMA clusters. T1: bijective XCD swizzle.
__global__ __launch_bounds__(512, 2) void gemm256(Slices sl, int ldc)
{
  __shared__ __align__(16) u16 Asm[2][256*64];
  __shared__ __align__(16) u16 Bsm[2][256*64];
  const int tid  = threadIdx.x;
  const int wave = tid >> 6;
  const int lane = tid & 63;
  const int lr = lane & 15;
  const int lq = lane >> 4;
  const int wm = wave >> 2;       // 2 in M (128 rows each)
  const int wn = wave & 3;        // 4 in N (64 cols each)

  // XCD-aware bijective swizzle: nwg=256, each XCD gets 32 contiguous wgids
  // -> one full (m-tile, kslice) row of n-tiles per XCD (A-panel L2-resident)
  const int bid = blockIdx.x;
  const int wg  = (bid & 7)*32 + (bid >> 3);
  const int bx  = wg & 31;
  const int by  = (wg >> 5) & 1;
  const int bz  = wg >> 6;
  const int m0 = by*256, n0 = bx*256;
  const Slice& sp = sl.s[bz];
  const u16* __restrict__ Ap = sp.A;
  const u16* __restrict__ Wp = sp.W;
  float* __restrict__ C = sp.C;
  const int lda = sp.lda, ldw = sp.ldw;
  const int nt = sp.K >> 6;

  f32x4 acc[8][4];
  #pragma unroll
  for (int i = 0; i < 8; i++)
    #pragma unroll
    for (int j = 0; j < 4; j++) acc[i][j] = (f32x4){0.f,0.f,0.f,0.f};

  auto stage = [&](int kt, int bsel){
    const int kcol = kt << 6;
    #pragma unroll
    for (int it = 0; it < 4; it++){
      const int cbk = it*512 + wave*64;
      const int c   = cbk + lane;
      const int row = c >> 3;
      const int c8  = (c & 7) ^ (row & 7);
      load_lds16(Ap + (size_t)(m0 + row)*lda + kcol + c8*8, &Asm[bsel][cbk*8]);
    }
    #pragma unroll
    for (int it = 0; it < 4; it++){
      const int cbk = it*512 + wave*64;
      const int c   = cbk + lane;
      const int row = c >> 3;
      const int c8  = (c & 7) ^ (row & 7);
      load_lds16(Wp + (size_t)(n0 + row)*ldw + kcol + c8*8, &Bsm[bsel][cbk*8]);
    }
  };

  stage(0, 0);
  for (int t = 0; t < nt; t++){
    const int cur = t & 1;
    if (t + 1 < nt){
      stage(t + 1, cur ^ 1);                       // 8 loads in flight across compute
      __builtin_amdgcn_sched_barrier(0);
      asm volatile("s_waitcnt vmcnt(8)" ::: "memory");   // tile t landed; t+1 still flying
    } else {
      asm volatile("s_waitcnt vmcnt(0)" ::: "memory");
    }
    __builtin_amdgcn_s_barrier();
    __builtin_amdgcn_sched_barrier(0);

    bf16x8 bfr[2][4];
    #pragma unroll
    for (int ks = 0; ks < 2; ks++)
      #pragma unroll
      for (int j = 0; j < 4; j++){
        const int row = wn*64 + j*16 + lr;
        const int xx = (ks*4 + lq) ^ (row & 7);
        bfr[ks][j] = *(const bf16x8*)&Bsm[cur][row*64 + xx*8];
      }
    #pragma unroll
    for (int i = 0; i < 8; i++){
      const int row = wm*128 + i*16 + lr;
      const bf16x8 a0 = *(const bf16x8*)&Asm[cur][row*64 + ((lq    ) ^ (row & 7))*8];
      const bf16x8 a1 = *(const bf16x8*)&Asm[cur][row*64 + ((4 + lq) ^ (row & 7))*8];
      __builtin_amdgcn_s_setprio(1);
      #pragma unroll
      for (int j = 0; j < 4; j++){
        acc[i][j] = __builtin_amdgcn_mfma_f32_16x16x32_bf16(a0, bfr[0][j], acc[i][j], 0, 0, 0);
        acc[i][j] = __builtin_amdgcn_mfma_f32_16x16x32_bf16(a1, bfr[1][j], acc[i][j], 0, 0, 0);
      }
      __builtin_amdgcn_s_setprio(0);
    }
    __builtin_amdgcn_sched_barrier(0);
    __builtin_amdgcn_s_barrier();                  // buf[cur] free for next prefetch
  }

  // C/D layout: col=lane&15, row=(lane>>4)*4+reg (m89-verified)
  #pragma unroll
  for (int i = 0; i < 8; i++){
    const int gmr = m0 + wm*128 + i*16 + lq*4;
    #pragma unroll
    for (int j = 0; j < 4; j++){
      const int gn = n0 + wn*64 + j*16 + lr;
      #pragma unroll
      for (int r = 0; r < 4; r++)
        C[(size_t)(gmr + r)*ldc + gn] = acc[i][j][r];
    }
  }
}

// ---------------- LSTM pointwise (+bias +4-way partial sum +block stats) ----------------
__global__ __launch_bounds__(256) void lstm_kernel(
    const float* __restrict__ g, const float* __restrict__ bias,
    float* __restrict__ c, float* __restrict__ h, float* __restrict__ ps)
{
  const int idx = blockIdx.x*256 + threadIdx.x;  // < 262144
  const int m = idx >> 9;
  const int q = idx & 511;
  const size_t gb = (size_t)m*G4 + q*4;
  const float* g1 = g + 4194304;
  const float* g2 = g + 2*4194304;
  const float* g3 = g + 3*4194304;
  f32x4 gi = *(const f32x4*)&g[gb]         + *(const f32x4*)&g1[gb]         + *(const f32x4*)&g2[gb]         + *(const f32x4*)&g3[gb]         + *(const f32x4*)&bias[q*4];
  f32x4 gf = *(const f32x4*)&g[gb+HID]     + *(const f32x4*)&g1[gb+HID]     + *(const f32x4*)&g2[gb+HID]     + *(const f32x4*)&g3[gb+HID]     + *(const f32x4*)&bias[HID+q*4];
  f32x4 gg = *(const f32x4*)&g[gb+2*HID]   + *(const f32x4*)&g1[gb+2*HID]   + *(const f32x4*)&g2[gb+2*HID]   + *(const f32x4*)&g3[gb+2*HID]   + *(const f32x4*)&bias[2*HID+q*4];
  f32x4 go = *(const f32x4*)&g[gb+3*HID]   + *(const f32x4*)&g1[gb+3*HID]   + *(const f32x4*)&g2[gb+3*HID]   + *(const f32x4*)&g3[gb+3*HID]   + *(const f32x4*)&bias[3*HID+q*4];
  const size_t cb = (size_t)m*HID + q*4;
  f32x4 cv = *(const f32x4*)&c[cb];
  f32x4 cn, hn;
  #pragma unroll
  for (int k = 0; k < 4; k++){
    const float ck = sigm(gf[k])*cv[k] + sigm(gi[k])*tanhf(gg[k]);
    cn[k] = ck;
    hn[k] = sigm(go[k])*tanhf(ck);
  }
  *(f32x4*)&c[cb] = cn;
  *(f32x4*)&h[cb] = hn;
  float s1 = hn[0]+hn[1]+hn[2]+hn[3];
  float s2 = hn[0]*hn[0]+hn[1]*hn[1]+hn[2]*hn[2]+hn[3]*hn[3];
  s1 = wsum(s1); s2 = wsum(s2);
  __shared__ float r1[4], r2[4];
  const int w = threadIdx.x >> 6;
  if ((threadIdx.x & 63) == 0){ r1[w] = s1; r2[w] = s2; }
  __syncthreads();
  if (threadIdx.x == 0){
    ps[blockIdx.x]        = r1[0]+r1[1]+r1[2]+r1[3];
    ps[1024 + blockIdx.x] = r2[0]+r2[1]+r2[2]+r2[3];
  }
}

// ---------------- MDL sum-exp pass ----------------
__global__ __launch_bounds__(256) void sumexp_kernel(
    const float* __restrict__ h, const float* __restrict__ ps, float* __restrict__ pe)
{
  const int tid = threadIdx.x;
  float t1 = 0.f, t2 = 0.f;
  for (int i = tid; i < 1024; i += 256){ t1 += ps[i]; t2 += ps[1024 + i]; }
  t1 = wsum(t1); t2 = wsum(t2);
  __shared__ float r1[4], r2[4];
  const int w = tid >> 6;
  if ((tid & 63) == 0){ r1[w] = t1; r2[w] = t2; }
  __syncthreads();
  __shared__ float mh[2];
  if (tid == 0){
    const float S1 = r1[0]+r1[1]+r1[2]+r1[3];
    const float S2 = r2[0]+r2[1]+r2[2]+r2[3];
    const float mean = S1*(1.f/1048576.f);
    const float var  = (S2 - 1048576.f*mean*mean)*(1.f/1048575.f);
    mh[0] = mean; mh[1] = 1.f/sqrtf(var);
  }
  __syncthreads();
  const float mean = mh[0], istd = mh[1];
  float se = 0.f;
  for (int i = blockIdx.x*256 + tid; i < (1<<18); i += 256*256){
    f32x4 v = ((const f32x4*)h)[i];
    #pragma unroll
    for (int k = 0; k < 4; k++){
      const float u = (v[k] - mean)*istd;
      se += expf(-0.5f*u*u);
    }
  }
  se = wsum(se);
  __shared__ float r3[4];
  if ((tid & 63) == 0) r3[w] = se;
  __syncthreads();
  if (tid == 0) pe[blockIdx.x] = r3[0]+r3[1]+r3[2]+r3[3];
}

// ---------------- MDL scale (writes bf16 h to 1-2 strided destinations) ----------------
__global__ __launch_bounds__(256) void scale_kernel(
    const float* __restrict__ h, const float* __restrict__ ps,
    const float* __restrict__ pe, u16* __restrict__ d1, int ld1,
    u16* __restrict__ d2, int ld2)
{
  const int tid = threadIdx.x;
  float t1 = 0.f, t2 = 0.f;
  for (int i = tid; i < 1024; i += 256){ t1 += ps[i]; t2 += ps[1024 + i]; }
  float t3 = pe[tid];
  t1 = wsum(t1); t2 = wsum(t2); t3 = wsum(t3);
  __shared__ float r1[4], r2[4], r3[4];
  const int w = tid >> 6;
  if ((tid & 63) == 0){ r1[w] = t1; r2[w] = t2; r3[w] = t3; }
  __syncthreads();
  __shared__ float lsh;
  if (tid == 0){
    const float S1 = r1[0]+r1[1]+r1[2]+r1[3];
    const float S2 = r2[0]+r2[1]+r2[2]+r2[3];
    const float SE = r3[0]+r3[1]+r3[2]+r3[3];
    const float mean = S1*(1.f/1048576.f);
    const float var  = (S2 - 1048576.f*mean*mean)*(1.f/1048575.f);
    const float stdv = sqrtf(var);
    const float lse = logf(SE) - logf(stdv) - 0.5f*LOG2PI_F;
    lsh = fmaxf(-lse, 0.f) + log1pf(expf(-fabsf(lse)));   // logaddexp(0,lse)-lse
  }
  __syncthreads();
  const float l = lsh;
  const int i = blockIdx.x*256 + tid;   // < 262144
  const int row = i >> 9;
  const int c4  = i & 511;
  f32x4 v = ((const f32x4*)h)[i];
  u16x4 o;
  #pragma unroll
  for (int k = 0; k < 4; k++) o[k] = f2bf(v[k]*l);
  *(u16x4*)&d1[(size_t)row*ld1 + c4*4] = o;
  if (d2) *(u16x4*)&d2[(size_t)row*ld2 + c4*4] = o;
}

// ---------------- z = mu + exp(logsig)*eps -> decA col 0 (stride DECK) ----------------
__global__ __launch_bounds__(256) void z_kernel(
    const float* __restrict__ zp, const float* __restrict__ mu_b,
    const float* __restrict__ sig_b, const float* __restrict__ ep, u16* __restrict__ zo)
{
  const int idx = blockIdx.x*256 + threadIdx.x;  // < 65536
  const int m = idx >> 7;
  const int q = idx & 127;
  const size_t base = (size_t)m*1024 + q*4;
  f32x4 mu = *(const f32x4*)&zp[base] + *(const f32x4*)&zp[524288 + base]
           + *(const f32x4*)&zp[2*524288 + base] + *(const f32x4*)&zp[3*524288 + base]
           + *(const f32x4*)&mu_b[q*4];
  f32x4 ls = *(const f32x4*)&zp[base+512] + *(const f32x4*)&zp[524288 + base+512]
           + *(const f32x4*)&zp[2*524288 + base+512] + *(const f32x4*)&zp[3*524288 + base+512]
           + *(const f32x4*)&sig_b[q*4];
  f32x4 ev = *(const f32x4*)&ep[(size_t)m*512 + q*4];
  u16x4 o;
  #pragma unroll
  for (int k = 0; k < 4; k++) o[k] = f2bf(mu[k] + expf(ls[k])*ev[k]);
  *(u16x4*)&zo[(size_t)m*DECK + q*4] = o;
}

// ---------------- fused write: attn + canvas += (Fy^T @ w @ Fx)/gamma ----------------
__global__ __launch_bounds__(256) void write_fused(
    const float* __restrict__ wp, const float* __restrict__ w_b,
    const u16* __restrict__ hd, const float* __restrict__ attnW,
    const float* __restrict__ attn_b, float* __restrict__ canvas)
{
  const int b = blockIdx.x;
  const int tid = threadIdx.x;
  __shared__ float red[4][5];
  __shared__ float prm[5];
  __shared__ float inv[32];
  __shared__ float sW[1024];
  __shared__ __align__(16) float sF[32*132];
  __shared__ float sU[128*33];

  {
    float a0=0,a1=0,a2=0,a3=0,a4=0;
    const u16* h = hd + (size_t)b*DECK;
    for (int k = tid; k < HID; k += 256){
      const float hv = bf2f(h[k]);
      a0 += hv*attnW[k];
      a1 += hv*attnW[HID + k];
      a2 += hv*attnW[2*HID + k];
      a3 += hv*attnW[3*HID + k];
      a4 += hv*attnW[4*HID + k];
    }
    a0 = wsum(a0); a1 = wsum(a1); a2 = wsum(a2); a3 = wsum(a3); a4 = wsum(a4);
    if ((tid & 63) == 0){
      const int w = tid >> 6;
      red[w][0]=a0; red[w][1]=a1; red[w][2]=a2; red[w][3]=a3; red[w][4]=a4;
    }
  }
  for (int i = tid; i < 1024; i += 256)
    sW[i] = wp[(size_t)b*1024 + i] + wp[524288 + (size_t)b*1024 + i]
          + wp[2*524288 + (size_t)b*1024 + i] + wp[3*524288 + (size_t)b*1024 + i] + w_b[i];
  __syncthreads();
  if (tid < 5){
    const float p = red[0][tid]+red[1][tid]+red[2][tid]+red[3][tid] + attn_b[tid];
    float v;
    if (tid <= 1)      v = 64.5f*(p + 1.f);
    else if (tid == 2) v = 1.f/(2.f*expf(p));
    else if (tid == 3) v = (127.f/31.f)*expf(p);
    else               v = expf(p);
    prm[tid] = v;
  }
  __syncthreads();
  const float gx = prm[0], gy = prm[1], i2s = prm[2], dl = prm[3], gm = prm[4];

  auto genF = [&](float g0){
    for (int i = tid; i < 4096; i += 256){
      const int n = i >> 7, a = i & 127;
      const float mu = g0 + ((float)n - 16.5f)*dl;
      const float t = ((float)a - mu)*i2s;
      sF[n*132 + a] = expf(-t*t);
    }
    __syncthreads();
    if (tid < 32){
      float ssum = 0.f;
      for (int a = 0; a < 128; a++) ssum += sF[tid*132 + a];
      inv[tid] = 1.f/(ssum + 1e-9f);
    }
    __syncthreads();
    for (int i = tid; i < 4096; i += 256)
      sF[(i >> 7)*132 + (i & 127)] *= inv[i >> 7];
    __syncthreads();
  };

  genF(gy);   // Fy
  {
    const int Bg = tid & 31, mg = tid >> 5;
    float acc[4][4] = {};
    for (int n = 0; n < 32; n++){
      float fy[4], wv[4];
      #pragma unroll
      for (int i = 0; i < 4; i++) fy[i] = sF[n*132 + Bg + 32*i];
      #pragma unroll
      for (int j = 0; j < 4; j++) wv[j] = sW[n*32 + mg*4 + j];
      #pragma unroll
      for (int i = 0; i < 4; i++)
        #pragma unroll
        for (int j = 0; j < 4; j++) acc[i][j] += fy[i]*wv[j];
    }
    #pragma unroll
    for (int i = 0; i < 4; i++)
      #pragma unroll
      for (int j = 0; j < 4; j++)
        sU[(Bg + 32*i)*33 + mg*4 + j] = acc[i][j];
  }
  __syncthreads();
  genF(gx);   // Fx
  {
    const int Bg = tid & 31, ag = tid >> 5;
    float acc[64];
    #pragma unroll
    for (int k = 0; k < 64; k++) acc[k] = 0.f;
    for (int mm = 0; mm < 32; mm++){
      float u[4];
      #pragma unroll
      for (int i = 0; i < 4; i++) u[i] = sU[(Bg + 32*i)*33 + mm];
      f32x4 fx[4];
      #pragma unroll
      for (int k = 0; k < 4; k++) fx[k] = *(const f32x4*)&sF[mm*132 + ag*16 + k*4];
      #pragma unroll
      for (int i = 0; i < 4; i++)
        #pragma unroll
        for (int k = 0; k < 4; k++)
          #pragma unroll
          for (int cc = 0; cc < 4; cc++)
            acc[i*16 + k*4 + cc] += u[i]*fx[k][cc];
    }
    const float ig = 1.f/gm;
    #pragma unroll
    for (int i = 0; i < 4; i++){
      const int B_ = Bg + 32*i;
      #pragma unroll
      for (int k = 0; k < 4; k++){
        float* cp = &canvas[(size_t)b*ABF + B_*128 + ag*16 + k*4];
        f32x4 cv = *(const f32x4*)cp;
        #pragma unroll
        for (int cc = 0; cc < 4; cc++) cv[cc] += acc[i*16 + k*4 + cc]*ig;
        *(f32x4*)cp = cv;
      }
    }
  }
}

// ---------------- host ----------------
extern "C" void kernel_launch(void* const* d_in, const int* in_sizes, int n_in,
                              void* d_out, int out_size, void* d_ws, size_t ws_size,
                              hipStream_t stream)
{
  (void)in_sizes; (void)n_in; (void)out_size; (void)ws_size;
  const float* x      = (const float*)d_in[0];
  const float* eps    = (const float*)d_in[1];
  const float* encWih = (const float*)d_in[2];
  const float* encWhh = (const float*)d_in[3];
  const float* enc_b  = (const float*)d_in[4];
  const float* decWih = (const float*)d_in[5];
  const float* decWhh = (const float*)d_in[6];
  const float* dec_b  = (const float*)d_in[7];
  const float* muW    = (const float*)d_in[8];
  const float* mu_b   = (const float*)d_in[9];
  const float* sigW   = (const float*)d_in[10];
  const float* sig_b  = (const float*)d_in[11];
  const float* attnW  = (const float*)d_in[12];
  const float* attn_b = (const float*)d_in[13];
  const float* wW     = (const float*)d_in[14];
  const float* w_b    = (const float*)d_in[15];
  float* canvas = (float*)d_out;

  char* wsb = (char*)d_ws;
  size_t off = 0;
  auto alloc = [&](size_t bytes)->char*{
    char* p = wsb + off; off += (bytes + 255) & ~(size_t)255; return p;
  };
  // zeroed state region (contiguous, first): c_enc, c_dec, encA, decA
  float* c_enc = (float*)alloc(1048576*4);
  float* c_dec = (float*)alloc(1048576*4);
  u16*   encA  = (u16*)  alloc((size_t)BSZ*ENCK*2);   // [r | h_dec | h_enc]
  u16*   decA  = (u16*)  alloc((size_t)BSZ*DECK*2);   // [z | h_dec]
  const size_t state_bytes = off;
  // transients
  float* ps    = (float*)alloc(2304*4);
  float* pe    = (float*)alloc(256*4);
  float* h_tmp = (float*)alloc(1048576*4);
  float* g_buf = (float*)alloc((size_t)4*4194304*4);   // 4 split-K partials
  float* zbuf  = g_buf;                  // alias: lifetime disjoint from g use
  float* wbuf  = g_buf + 2097152;        // alias
  u16*   x_bf  = (u16*)  alloc((size_t)8388608*2);
  // bf16 weights (concatenated along K)
  u16* encW    = (u16*)alloc((size_t)G4*ENCK*2);   // [Wih | Whh]  (8192 x 6144)
  u16* decW    = (u16*)alloc((size_t)G4*DECK*2);   // [dWih | dWhh] (8192 x 2560)
  u16* muw_bf  = (u16*)alloc((size_t)1048576*2);
  u16* sigw_bf = (u16*)alloc((size_t)1048576*2);
  u16* ww_bf   = (u16*)alloc((size_t)2097152*2);

  // init
  zero_kernel<<<1024, 256, 0, stream>>>((float*)wsb, (int)(state_bytes/16));
  zero_kernel<<<2048, 256, 0, stream>>>(canvas, (ABF/4)*BSZ);
  cvt_kernel<<<2048, 256, 0, stream>>>(x,    x_bf,   8388608/4);
  // encW = [Wih (srcC 4096) | Whh (srcC 2048)], stride 6144
  cvt_strided_kernel<<<2048, 256, 0, stream>>>(encWih, encW, 8388608, 10, 1023, ENCK, 0);
  cvt_strided_kernel<<<2048, 256, 0, stream>>>(encWhh, encW, 4194304,  9,  511, ENCK, 4096);
  // decW = [dWih (srcC 512) | dWhh (srcC 2048)], stride 2560
  cvt_strided_kernel<<<1024, 256, 0, stream>>>(decWih, decW, 1048576,  7,  127, DECK, 0);
  cvt_strided_kernel<<<2048, 256, 0, stream>>>(decWhh, decW, 4194304,  9,  511, DECK, 512);
  cvt_kernel<<<512,  256, 0, stream>>>(muW,  muw_bf,  1048576/4);
  cvt_kernel<<<512,  256, 0, stream>>>(sigW, sigw_bf, 1048576/4);
  cvt_kernel<<<512,  256, 0, stream>>>(wW,   ww_bf,   2097152/4);

  Slices enc_sl = {};
  for (int k = 0; k < 4; k++)
    enc_sl.s[k] = { encA + 1536*k, encW + 1536*k, nullptr, g_buf + (size_t)k*4194304, ENCK, ENCK, 1536, 0 };

  Slices dec_sl = {};
  for (int k = 0; k < 4; k++)
    dec_sl.s[k] = { decA + 640*k, decW + 640*k, nullptr, g_buf + (size_t)k*4194304, DECK, DECK, 640, 0 };

  Slices ms_sl = {}, w_sl = {};
  for (int k = 0; k < 4; k++){
    ms_sl.s[k] = { encA + 4096 + 512*k, muw_bf + 512*k, sigw_bf + 512*k, zbuf + (size_t)k*524288, ENCK, HID, 512, 0 };
    w_sl.s[k]  = { decA + 512  + 512*k, ww_bf  + 512*k, nullptr,         wbuf + (size_t)k*524288, DECK, HID, 512, 0 };
  }

  for (int t = 0; t < TSTEPS; t++){
    // read phase (attn from pre-update h_dec in decA, glimpse -> encA cols 0:2048)
    read_fused<<<512, 256, 0, stream>>>(x_bf, canvas, decA + 512, attnW, attn_b, encA);
    // encoder gates: 256x256 pipelined GEMM, split-K 4 over concat K=6144
    gemm256<<<256, 512, 0, stream>>>(enc_sl, G4);
    lstm_kernel<<<1024, 256, 0, stream>>>(g_buf, enc_b, c_enc, h_tmp, ps);
    sumexp_kernel<<<256, 256, 0, stream>>>(h_tmp, ps, pe);
    scale_kernel<<<1024, 256, 0, stream>>>(h_tmp, ps, pe, encA + 4096, ENCK, nullptr, 0);
    // mu | logsigma fused GEMM, split-K 4-way (n>=512 -> sig_W)
    gemm_bt<64,64><<<dim3(16,8,4), 256, 0, stream>>>(ms_sl, 512, 1024);
    z_kernel<<<256, 256, 0, stream>>>(zbuf, mu_b, sig_b, eps + (size_t)t*BSZ*ZD, decA);
    // decoder gates: split-K 4 over concat K=2560
    gemm256<<<256, 512, 0, stream>>>(dec_sl, G4);
    lstm_kernel<<<1024, 256, 0, stream>>>(g_buf, dec_b, c_dec, h_tmp, ps);
    sumexp_kernel<<<256, 256, 0, stream>>>(h_tmp, ps, pe);
    scale_kernel<<<1024, 256, 0, stream>>>(h_tmp, ps, pe, decA + 512, DECK, encA + 2048, ENCK);
    // write phase (attn from updated h_dec)
    gemm_bt<64,64><<<dim3(16,8,4), 256, 0, stream>>>(w_sl, 0, 1024);
    write_fused<<<512, 256, 0, stream>>>(wbuf, w_b, decA + 512, attnW, attn_b, canvas);
  }
}

// Round 2
// 3601.534 us; speedup vs baseline: 1.2056x; 1.1486x over previous
//
#include <hip/hip_runtime.h>
#include <math.h>

#define BSZ   512
#define TSTEPS 16
#define HID   2048
#define G4    8192
#define ZD    512
#define ABF   16384
#define ENCK  6144   // [r(2048) | h_dec(2048) | h_enc(2048)]
#define DECK  2560   // [z(512) | h_dec(2048)]
#define LOG2PI_F 1.8378770664093453f

typedef float  f32x4  __attribute__((ext_vector_type(4)));
typedef __bf16 bf16x8 __attribute__((ext_vector_type(8)));
typedef unsigned short u16;
typedef u16 u16x4 __attribute__((ext_vector_type(4)));
typedef u16 u16x8v __attribute__((ext_vector_type(8)));
union bfcast { u16x8v u; bf16x8 b; };

__device__ __forceinline__ u16 f2bf(float f){
  union { float f; unsigned u; } v; v.f = f;
  unsigned u = v.u;
  return (u16)((u + 0x7FFFu + ((u >> 16) & 1u)) >> 16);   // RNE
}
__device__ __forceinline__ float bf2f(u16 u){
  union { unsigned u; float f; } v; v.u = ((unsigned)u) << 16; return v.f;
}
__device__ __forceinline__ float sigm(float x){ return 1.f/(1.f + expf(-x)); }

__device__ __forceinline__ void load_lds16(const void* g, void* l){
  __builtin_amdgcn_global_load_lds(
      (const __attribute__((address_space(1))) void*)g,
      (__attribute__((address_space(3))) void*)l, 16, 0, 0);
}

__device__ __forceinline__ float wsum(float v){
  #pragma unroll
  for (int o = 32; o; o >>= 1) v += __shfl_down(v, o, 64);
  return v;
}

// ---------------- utility kernels ----------------
__global__ __launch_bounds__(256) void zero_kernel(float* __restrict__ p, int n4){
  int i = blockIdx.x*256 + threadIdx.x;
  const int st = gridDim.x*256;
  f32x4 z = {0.f,0.f,0.f,0.f};
  for (; i < n4; i += st) ((f32x4*)p)[i] = z;
}

__global__ __launch_bounds__(256) void cvt_kernel(const float* __restrict__ s, u16* __restrict__ d, int n4){
  int i = blockIdx.x*256 + threadIdx.x;
  const int st = gridDim.x*256;
  for (; i < n4; i += st){
    f32x4 v = ((const f32x4*)s)[i];
    u16x4 o;
    o[0]=f2bf(v[0]); o[1]=f2bf(v[1]); o[2]=f2bf(v[2]); o[3]=f2bf(v[3]);
    ((u16x4*)d)[i] = o;
  }
}

// f32 [rows x srcC] -> bf16 strided dst (dst row stride dstride elems, col offset coloff)
__global__ __launch_bounds__(256) void cvt_strided_kernel(
    const float* __restrict__ s, u16* __restrict__ d,
    int n4, int sh, int cmask, int dstride, int coloff)
{
  int i = blockIdx.x*256 + threadIdx.x;
  const int st = gridDim.x*256;
  for (; i < n4; i += st){
    f32x4 v = ((const f32x4*)s)[i];
    u16x4 o;
    o[0]=f2bf(v[0]); o[1]=f2bf(v[1]); o[2]=f2bf(v[2]); o[3]=f2bf(v[3]);
    const int row = i >> sh;
    const int c4  = i & cmask;
    *(u16x4*)&d[(size_t)row*dstride + coloff + c4*4] = o;
  }
}

// ---------------- fused read: attn + xhat + glimpse (MFMA) ----------------
__global__ __launch_bounds__(256) void read_fused(
    const u16* __restrict__ x_bf, const float* __restrict__ canvas,
    const u16* __restrict__ hd, const float* __restrict__ attnW,
    const float* __restrict__ attn_b, u16* __restrict__ r_out)
{
  const int b = blockIdx.x;
  const int tid = threadIdx.x;
  const int wave = tid >> 6;
  const int lane = tid & 63;
  const int lr = lane & 15;
  const int lq = lane >> 4;
  __shared__ float red[4][5];
  __shared__ float prm[5];
  __shared__ float rowsum[32][9];
  __shared__ __align__(16) u16 Fxb[32*128];   // row n, 16B-chunk c stored at c^(n&7)
  __shared__ __align__(16) u16 Fyb[32*128];
  __shared__ __align__(16) u16 Ttx[32*136];   // T[m][B], pad to 136
  __shared__ __align__(16) u16 Ttxh[32*136];

  {
    float a0=0,a1=0,a2=0,a3=0,a4=0;
    const u16* h = hd + (size_t)b*DECK;
    for (int k = tid; k < HID; k += 256){
      const float hv = bf2f(h[k]);
      a0 += hv*attnW[k];
      a1 += hv*attnW[HID + k];
      a2 += hv*attnW[2*HID + k];
      a3 += hv*attnW[3*HID + k];
      a4 += hv*attnW[4*HID + k];
    }
    a0 = wsum(a0); a1 = wsum(a1); a2 = wsum(a2); a3 = wsum(a3); a4 = wsum(a4);
    if (lane == 0){
      red[wave][0]=a0; red[wave][1]=a1; red[wave][2]=a2; red[wave][3]=a3; red[wave][4]=a4;
    }
  }
  __syncthreads();
  if (tid < 5){
    const float p = red[0][tid]+red[1][tid]+red[2][tid]+red[3][tid] + attn_b[tid];
    float v;
    if (tid <= 1)      v = 64.5f*(p + 1.f);
    else if (tid == 2) v = 1.f/(2.f*expf(p));       // i2s
    else if (tid == 3) v = (127.f/31.f)*expf(p);    // delta
    else               v = expf(p);                  // gamma
    prm[tid] = v;
  }
  __syncthreads();
  const float gx = prm[0], gy = prm[1], i2s = prm[2], dl = prm[3], gm = prm[4];

  auto genF = [&](float g0, u16* dst){
    const int rr = tid >> 3;
    const int asub = tid & 7;
    const float mu = g0 + ((float)rr - 16.5f)*dl;
    float s = 0.f;
    for (int a = asub*16; a < asub*16 + 16; a++){
      const float t = ((float)a - mu)*i2s;
      s += expf(-t*t);
    }
    rowsum[rr][asub] = s;
    __syncthreads();
    if (tid < 32){
      float tot = 0.f;
      #pragma unroll
      for (int j = 0; j < 8; j++) tot += rowsum[tid][j];
      rowsum[tid][8] = 1.f/(tot + 1e-9f);
    }
    __syncthreads();
    for (int i = tid; i < 4096; i += 256){
      const int n = i >> 7, a = i & 127;
      const float mu2 = g0 + ((float)n - 16.5f)*dl;
      const float t = ((float)a - mu2)*i2s;
      const float v = expf(-t*t)*rowsum[n][8];
      const int pos = (a >> 3) ^ (n & 7);
      dst[n*128 + pos*8 + (a & 7)] = f2bf(v);
    }
    __syncthreads();
  };
  genF(gx, Fxb);
  genF(gy, Fyb);

  const u16*   xb = x_bf   + (size_t)b*ABF;
  const float* cb = canvas + (size_t)b*ABF;
  f32x4 Cx[2][2], Ch[2][2];
  #pragma unroll
  for (int i = 0; i < 2; i++)
    #pragma unroll
    for (int j = 0; j < 2; j++){ Cx[i][j] = (f32x4){0,0,0,0}; Ch[i][j] = (f32x4){0,0,0,0}; }

  #pragma unroll
  for (int mt = 0; mt < 2; mt++){
    const int row = wave*32 + mt*16 + lr;
    bfcast ax[4], ah[4];
    #pragma unroll
    for (int ks = 0; ks < 4; ks++){
      const int base = row*128 + ks*32 + lq*8;
      ax[ks].u = *(const u16x8v*)&xb[base];
      f32x4 c0 = *(const f32x4*)&cb[base];
      f32x4 c1 = *(const f32x4*)&cb[base + 4];
      #pragma unroll
      for (int j = 0; j < 4; j++){
        ah[ks].u[j]   = f2bf(bf2f(ax[ks].u[j])   - sigm(c0[j]));
        ah[ks].u[4+j] = f2bf(bf2f(ax[ks].u[4+j]) - sigm(c1[j]));
      }
    }
    #pragma unroll
    for (int nt = 0; nt < 2; nt++){
      #pragma unroll
      for (int ks = 0; ks < 4; ks++){
        const int pos = (ks*4 + lq) ^ (lr & 7);
        bf16x8 bf_ = *(const bf16x8*)&Fxb[(nt*16 + lr)*128 + pos*8];
        Cx[mt][nt] = __builtin_amdgcn_mfma_f32_16x16x32_bf16(ax[ks].b, bf_, Cx[mt][nt], 0, 0, 0);
        Ch[mt][nt] = __builtin_amdgcn_mfma_f32_16x16x32_bf16(ah[ks].b, bf_, Ch[mt][nt], 0, 0, 0);
      }
    }
  }
  #pragma unroll
  for (int mt = 0; mt < 2; mt++)
    #pragma unroll
    for (int nt = 0; nt < 2; nt++)
      #pragma unroll
      for (int r = 0; r < 4; r++){
        const int m  = nt*16 + lr;
        const int B_ = wave*32 + mt*16 + lq*4 + r;
        Ttx[m*136 + B_]  = f2bf(Cx[mt][nt][r]);
        Ttxh[m*136 + B_] = f2bf(Ch[mt][nt][r]);
      }
  __syncthreads();

  const int mat = wave >> 1;           // 0: x, 1: xhat
  const u16* Tt = mat ? Ttxh : Ttx;
  const int ntl = wave & 1;            // n-half
  f32x4 R[2];
  R[0] = (f32x4){0,0,0,0}; R[1] = (f32x4){0,0,0,0};
  #pragma unroll
  for (int ks = 0; ks < 4; ks++){
    const int pos = (ks*4 + lq) ^ (lr & 7);
    bf16x8 af = *(const bf16x8*)&Fyb[(ntl*16 + lr)*128 + pos*8];
    #pragma unroll
    for (int mt = 0; mt < 2; mt++){
      bf16x8 bf_ = *(const bf16x8*)&Tt[(mt*16 + lr)*136 + ks*32 + lq*8];
      R[mt] = __builtin_amdgcn_mfma_f32_16x16x32_bf16(af, bf_, R[mt], 0, 0, 0);
    }
  }
  #pragma unroll
  for (int mt = 0; mt < 2; mt++){
    const int m = mt*16 + lr;
    #pragma unroll
    for (int r = 0; r < 4; r++){
      const int n = ntl*16 + lq*4 + r;
      r_out[(size_t)b*ENCK + mat*1024 + n*32 + m] = f2bf(R[mt][r]*gm);
    }
  }
}

// ---------------- bf16 B^T GEMM structs ----------------
struct Slice { const u16* A; const u16* W; const u16* Whi; float* C; int lda, ldw, K, pad; };
struct Slices { Slice s[4]; };

// ---------------- small-tile GEMM (ms / w) ----------------
template<int BM, int BN>
__global__ __launch_bounds__(256) void gemm_bt(Slices sl, int nsplit, int ldc)
{
  constexpr int BK = 64;
  constexpr int FI = BM/32;
  constexpr int FJ = BN/32;
  __shared__ __align__(16) u16 Asm[BM*BK];
  __shared__ __align__(16) u16 Bsm[BN*BK];
  const int tid  = threadIdx.x;
  const int wave = tid >> 6;
  const int lane = tid & 63;
  const int wm = wave & 1, wn = wave >> 1;
  const int m0 = blockIdx.y * BM;
  const int n0 = blockIdx.x * BN;
  const Slice& sp = sl.s[blockIdx.z];
  const u16* Ap = sp.A;
  const u16* Wp = sp.W;
  const int lda = sp.lda, ldw = sp.ldw, K = sp.K;
  if (nsplit > 0 && n0 >= nsplit) Wp = sp.Whi - (size_t)nsplit * ldw;
  float* C = sp.C;

  f32x4 acc[FI][FJ];
  #pragma unroll
  for (int i = 0; i < FI; i++)
    #pragma unroll
    for (int j = 0; j < FJ; j++) acc[i][j] = (f32x4){0.f,0.f,0.f,0.f};

  const int lr = lane & 15;
  const int lq = lane >> 4;

  for (int kt = 0; kt < K; kt += BK){
    __syncthreads();
    constexpr int NCA = BM*BK/8;
    #pragma unroll
    for (int it = 0; it < NCA/256; it++){
      const int cb = it*256 + wave*64;
      const int c  = cb + lane;
      const int row = c >> 3;
      const int c8  = (c & 7) ^ (row & 7);
      load_lds16(Ap + (size_t)(m0 + row)*lda + kt + c8*8, &Asm[cb*8]);
    }
    constexpr int NCB = BN*BK/8;
    #pragma unroll
    for (int it = 0; it < NCB/256; it++){
      const int cb = it*256 + wave*64;
      const int c  = cb + lane;
      const int row = c >> 3;
      const int c8  = (c & 7) ^ (row & 7);
      load_lds16(Wp + (size_t)(n0 + row)*ldw + kt + c8*8, &Bsm[cb*8]);
    }
    __syncthreads();
    #pragma unroll
    for (int ks = 0; ks < 2; ks++){
      bf16x8 af[FI], bfr[FJ];
      #pragma unroll
      for (int i = 0; i < FI; i++){
        const int row = wm*(BM/2) + i*16 + lr;
        const int xx = (ks*4 + lq) ^ (row & 7);
        af[i] = *(const bf16x8*)&Asm[row*BK + xx*8];
      }
      #pragma unroll
      for (int j = 0; j < FJ; j++){
        const int row = wn*(BN/2) + j*16 + lr;
        const int xx = (ks*4 + lq) ^ (row & 7);
        bfr[j] = *(const bf16x8*)&Bsm[row*BK + xx*8];
      }
      #pragma unroll
      for (int i = 0; i < FI; i++)
        #pragma unroll
        for (int j = 0; j < FJ; j++)
          acc[i][j] = __builtin_amdgcn_mfma_f32_16x16x32_bf16(af[i], bfr[j], acc[i][j], 0, 0, 0);
    }
  }
  #pragma unroll
  for (int i = 0; i < FI; i++){
    const int gm = m0 + wm*(BM/2) + i*16 + lq*4;
    #pragma unroll
    for (int j = 0; j < FJ; j++){
      const int gn = n0 + wn*(BN/2) + j*16 + lr;
      #pragma unroll
      for (int r = 0; r < 4; r++)
        C[(size_t)(gm + r)*ldc + gn] = acc[i][j][r];
    }
  }
}

// ---------------- phased big GEMM: 256M x 128N x BK=64, triple-buffer, 2 phases/K-tile ----
// grid = 64n x 2m x 2ksplit = 256 blocks = 1/CU. LDS 144 KiB. 8 waves: wm=wave>>1 (4 in M),
// wn=wave&1 (2 in N); per-wave C = 64x64 (acc[4][4]).
// Pipeline: tile t in buf t%3; iter t stages tile t+2 into buf (t+2)%3 (slot last read at
// iter t-1, separated by barriers -> WAR-safe). Counted vmcnt(6) once per K-tile at phase 1
// drains tile t+1's 6 loads while tile t+2's 6 stay in flight (never 0 mid-loop).
// Phase = {8 ds_read_b128 + stage issue} -> s_barrier -> lgkmcnt(0) -> 16 MFMA -> s_barrier.
// Cross-wave LDS visibility: each tile's reads are preceded (in an earlier phase) by
// all-waves [own-vmcnt -> s_barrier]; prologue vmcnt(6)+barrier seeds the chain.
__global__ __launch_bounds__(512, 2) void gemm_ph(Slices sl, int ldc)
{
  __shared__ __align__(16) u16 Asm[3][256*64];
  __shared__ __align__(16) u16 Bsm[3][128*64];
  const int tid  = threadIdx.x;
  const int wave = tid >> 6;
  const int lane = tid & 63;
  const int lr = lane & 15;
  const int lq = lane >> 4;
  const int wm = wave >> 1;       // 0..3 -> rows wm*64..+63
  const int wn = wave & 1;        // 0..1 -> cols wn*64..+63

  // XCD-aware swizzle: 256 wgs, XCD x gets wg x*32..x*32+31 -> same (m-tile,kslice), all n
  const int bid = blockIdx.x;
  const int wg  = (bid & 7)*32 + (bid >> 3);
  const int bx  = wg & 63;
  const int by  = (wg >> 6) & 1;
  const int bz  = wg >> 7;
  const int m0 = by*256, n0 = bx*128;
  const Slice& sp = sl.s[bz];
  const u16* __restrict__ Ap = sp.A;
  const u16* __restrict__ Wp = sp.W;
  float* __restrict__ C = sp.C;
  const int lda = sp.lda, ldw = sp.ldw;
  const int nt = sp.K >> 6;

  f32x4 acc[4][4];
  #pragma unroll
  for (int i = 0; i < 4; i++)
    #pragma unroll
    for (int j = 0; j < 4; j++) acc[i][j] = (f32x4){0.f,0.f,0.f,0.f};

  auto stageA = [&](int kt, int bsel, int half){   // rows half*128..+127 : 2 loads/thread
    const int kcol = kt << 6;
    #pragma unroll
    for (int it = 0; it < 2; it++){
      const int cbk = (half*2 + it)*512 + wave*64;
      const int c   = cbk + lane;
      const int row = c >> 3;
      const int c8  = (c & 7) ^ (row & 7);
      load_lds16(Ap + (size_t)(m0 + row)*lda + kcol + c8*8, &Asm[bsel][cbk*8]);
    }
  };
  auto stageB = [&](int kt, int bsel){             // 128 rows : 2 loads/thread
    const int kcol = kt << 6;
    #pragma unroll
    for (int it = 0; it < 2; it++){
      const int cbk = it*512 + wave*64;
      const int c   = cbk + lane;
      const int row = c >> 3;
      const int c8  = (c & 7) ^ (row & 7);
      load_lds16(Wp + (size_t)(n0 + row)*ldw + kcol + c8*8, &Bsm[bsel][cbk*8]);
    }
  };

  // prologue: tiles 0,1 staged; wait tile0 (6 newest = tile1 in flight)
  stageA(0, 0, 0); stageA(0, 0, 1); stageB(0, 0);
  stageA(1, 1, 0); stageA(1, 1, 1); stageB(1, 1);
  asm volatile("s_waitcnt vmcnt(6)" ::: "memory");
  __builtin_amdgcn_s_barrier();

  int b = 0;
  for (int t = 0; t < nt; t++){
    const int bs = (b == 0) ? 2 : b - 1;   // (b+2)%3
    const bool pf   = (t + 2 < nt);
    const bool more = (t + 1 < nt);

    // ---- phase 0 (ks=0) ----
    bf16x8 a0[4], b0[4];
    #pragma unroll
    for (int j = 0; j < 4; j++){
      const int row = wn*64 + j*16 + lr;
      b0[j] = *(const bf16x8*)&Bsm[b][row*64 + ((lq) ^ (row & 7))*8];
    }
    #pragma unroll
    for (int i = 0; i < 4; i++){
      const int row = wm*64 + i*16 + lr;
      a0[i] = *(const bf16x8*)&Asm[b][row*64 + ((lq) ^ (row & 7))*8];
    }
    if (pf){ stageA(t+2, bs, 0); stageA(t+2, bs, 1); }
    __builtin_amdgcn_sched_barrier(0);
    __builtin_amdgcn_s_barrier();
    asm volatile("s_waitcnt lgkmcnt(0)" ::: "memory");
    __builtin_amdgcn_sched_barrier(0);
    __builtin_amdgcn_s_setprio(1);
    #pragma unroll
    for (int i = 0; i < 4; i++)
      #pragma unroll
      for (int j = 0; j < 4; j++)
        acc[i][j] = __builtin_amdgcn_mfma_f32_16x16x32_bf16(a0[i], b0[j], acc[i][j], 0, 0, 0);
    __builtin_amdgcn_s_setprio(0);
    __builtin_amdgcn_sched_barrier(0);
    __builtin_amdgcn_s_barrier();

    // ---- phase 1 (ks=1) ----
    bf16x8 a1[4], b1[4];
    #pragma unroll
    for (int j = 0; j < 4; j++){
      const int row = wn*64 + j*16 + lr;
      b1[j] = *(const bf16x8*)&Bsm[b][row*64 + ((4 + lq) ^ (row & 7))*8];
    }
    #pragma unroll
    for (int i = 0; i < 4; i++){
      const int row = wm*64 + i*16 + lr;
      a1[i] = *(const bf16x8*)&Asm[b][row*64 + ((4 + lq) ^ (row & 7))*8];
    }
    if (pf) stageB(t+2, bs);
    __builtin_amdgcn_sched_barrier(0);
    if (pf)        asm volatile("s_waitcnt vmcnt(6)" ::: "memory");  // drain tile t+1; t+2 flying
    else if (more) asm volatile("s_waitcnt vmcnt(0)" ::: "memory");  // last prefetch drain
    __builtin_amdgcn_s_barrier();
    asm volatile("s_waitcnt lgkmcnt(0)" ::: "memory");
    __builtin_amdgcn_sched_barrier(0);
    __builtin_amdgcn_s_setprio(1);
    #pragma unroll
    for (int i = 0; i < 4; i++)
      #pragma unroll
      for (int j = 0; j < 4; j++)
        acc[i][j] = __builtin_amdgcn_mfma_f32_16x16x32_bf16(a1[i], b1[j], acc[i][j], 0, 0, 0);
    __builtin_amdgcn_s_setprio(0);
    __builtin_amdgcn_sched_barrier(0);
    __builtin_amdgcn_s_barrier();

    b = (b == 2) ? 0 : b + 1;
  }

  // C/D layout: col=lane&15, row=(lane>>4)*4+reg (m89-verified)
  #pragma unroll
  for (int i = 0; i < 4; i++){
    const int gmr = m0 + wm*64 + i*16 + lq*4;
    #pragma unroll
    for (int j = 0; j < 4; j++){
      const int gn = n0 + wn*64 + j*16 + lr;
      #pragma unroll
      for (int r = 0; r < 4; r++)
        C[(size_t)(gmr + r)*ldc + gn] = acc[i][j][r];
    }
  }
}

// ---------------- LSTM pointwise (+bias +2-way partial sum +block stats) ----------------
__global__ __launch_bounds__(256) void lstm_kernel(
    const float* __restrict__ g, const float* __restrict__ bias,
    float* __restrict__ c, float* __restrict__ h, float* __restrict__ ps)
{
  const int idx = blockIdx.x*256 + threadIdx.x;  // < 262144
  const int m = idx >> 9;
  const int q = idx & 511;
  const size_t gb = (size_t)m*G4 + q*4;
  const float* g1 = g + 4194304;
  f32x4 gi = *(const f32x4*)&g[gb]       + *(const f32x4*)&g1[gb]       + *(const f32x4*)&bias[q*4];
  f32x4 gf = *(const f32x4*)&g[gb+HID]   + *(const f32x4*)&g1[gb+HID]   + *(const f32x4*)&bias[HID+q*4];
  f32x4 gg = *(const f32x4*)&g[gb+2*HID] + *(const f32x4*)&g1[gb+2*HID] + *(const f32x4*)&bias[2*HID+q*4];
  f32x4 go = *(const f32x4*)&g[gb+3*HID] + *(const f32x4*)&g1[gb+3*HID] + *(const f32x4*)&bias[3*HID+q*4];
  const size_t cb = (size_t)m*HID + q*4;
  f32x4 cv = *(const f32x4*)&c[cb];
  f32x4 cn, hn;
  #pragma unroll
  for (int k = 0; k < 4; k++){
    const float ck = sigm(gf[k])*cv[k] + sigm(gi[k])*tanhf(gg[k]);
    cn[k] = ck;
    hn[k] = sigm(go[k])*tanhf(ck);
  }
  *(f32x4*)&c[cb] = cn;
  *(f32x4*)&h[cb] = hn;
  float s1 = hn[0]+hn[1]+hn[2]+hn[3];
  float s2 = hn[0]*hn[0]+hn[1]*hn[1]+hn[2]*hn[2]+hn[3]*hn[3];
  s1 = wsum(s1); s2 = wsum(s2);
  __shared__ float r1[4], r2[4];
  const int w = threadIdx.x >> 6;
  if ((threadIdx.x & 63) == 0){ r1[w] = s1; r2[w] = s2; }
  __syncthreads();
  if (threadIdx.x == 0){
    ps[blockIdx.x]        = r1[0]+r1[1]+r1[2]+r1[3];
    ps[1024 + blockIdx.x] = r2[0]+r2[1]+r2[2]+r2[3];
  }
}

// ---------------- MDL sum-exp pass ----------------
__global__ __launch_bounds__(256) void sumexp_kernel(
    const float* __restrict__ h, const float* __restrict__ ps, float* __restrict__ pe)
{
  const int tid = threadIdx.x;
  float t1 = 0.f, t2 = 0.f;
  for (int i = tid; i < 1024; i += 256){ t1 += ps[i]; t2 += ps[1024 + i]; }
  t1 = wsum(t1); t2 = wsum(t2);
  __shared__ float r1[4], r2[4];
  const int w = tid >> 6;
  if ((tid & 63) == 0){ r1[w] = t1; r2[w] = t2; }
  __syncthreads();
  __shared__ float mh[2];
  if (tid == 0){
    const float S1 = r1[0]+r1[1]+r1[2]+r1[3];
    const float S2 = r2[0]+r2[1]+r2[2]+r2[3];
    const float mean = S1*(1.f/1048576.f);
    const float var  = (S2 - 1048576.f*mean*mean)*(1.f/1048575.f);
    mh[0] = mean; mh[1] = 1.f/sqrtf(var);
  }
  __syncthreads();
  const float mean = mh[0], istd = mh[1];
  float se = 0.f;
  for (int i = blockIdx.x*256 + tid; i < (1<<18); i += 256*256){
    f32x4 v = ((const f32x4*)h)[i];
    #pragma unroll
    for (int k = 0; k < 4; k++){
      const float u = (v[k] - mean)*istd;
      se += expf(-0.5f*u*u);
    }
  }
  se = wsum(se);
  __shared__ float r3[4];
  if ((tid & 63) == 0) r3[w] = se;
  __syncthreads();
  if (tid == 0) pe[blockIdx.x] = r3[0]+r3[1]+r3[2]+r3[3];
}

// ---------------- MDL scale (writes bf16 h to 1-2 strided destinations) ----------------
__global__ __launch_bounds__(256) void scale_kernel(
    const float* __restrict__ h, const float* __restrict__ ps,
    const float* __restrict__ pe, u16* __restrict__ d1, int ld1,
    u16* __restrict__ d2, int ld2)
{
  const int tid = threadIdx.x;
  float t1 = 0.f, t2 = 0.f;
  for (int i = tid; i < 1024; i += 256){ t1 += ps[i]; t2 += ps[1024 + i]; }
  float t3 = pe[tid];
  t1 = wsum(t1); t2 = wsum(t2); t3 = wsum(t3);
  __shared__ float r1[4], r2[4], r3[4];
  const int w = tid >> 6;
  if ((tid & 63) == 0){ r1[w] = t1; r2[w] = t2; r3[w] = t3; }
  __syncthreads();
  __shared__ float lsh;
  if (tid == 0){
    const float S1 = r1[0]+r1[1]+r1[2]+r1[3];
    const float S2 = r2[0]+r2[1]+r2[2]+r2[3];
    const float SE = r3[0]+r3[1]+r3[2]+r3[3];
    const float mean = S1*(1.f/1048576.f);
    const float var  = (S2 - 1048576.f*mean*mean)*(1.f/1048575.f);
    const float stdv = sqrtf(var);
    const float lse = logf(SE) - logf(stdv) - 0.5f*LOG2PI_F;
    lsh = fmaxf(-lse, 0.f) + log1pf(expf(-fabsf(lse)));   // logaddexp(0,lse)-lse
  }
  __syncthreads();
  const float l = lsh;
  const int i = blockIdx.x*256 + tid;   // < 262144
  const int row = i >> 9;
  const int c4  = i & 511;
  f32x4 v = ((const f32x4*)h)[i];
  u16x4 o;
  #pragma unroll
  for (int k = 0; k < 4; k++) o[k] = f2bf(v[k]*l);
  *(u16x4*)&d1[(size_t)row*ld1 + c4*4] = o;
  if (d2) *(u16x4*)&d2[(size_t)row*ld2 + c4*4] = o;
}

// ---------------- z = mu + exp(logsig)*eps -> decA col 0 (stride DECK) ----------------
__global__ __launch_bounds__(256) void z_kernel(
    const float* __restrict__ zp, const float* __restrict__ mu_b,
    const float* __restrict__ sig_b, const float* __restrict__ ep, u16* __restrict__ zo)
{
  const int idx = blockIdx.x*256 + threadIdx.x;  // < 65536
  const int m = idx >> 7;
  const int q = idx & 127;
  const size_t base = (size_t)m*1024 + q*4;
  f32x4 mu = *(const f32x4*)&zp[base] + *(const f32x4*)&zp[524288 + base]
           + *(const f32x4*)&zp[2*524288 + base] + *(const f32x4*)&zp[3*524288 + base]
           + *(const f32x4*)&mu_b[q*4];
  f32x4 ls = *(const f32x4*)&zp[base+512] + *(const f32x4*)&zp[524288 + base+512]
           + *(const f32x4*)&zp[2*524288 + base+512] + *(const f32x4*)&zp[3*524288 + base+512]
           + *(const f32x4*)&sig_b[q*4];
  f32x4 ev = *(const f32x4*)&ep[(size_t)m*512 + q*4];
  u16x4 o;
  #pragma unroll
  for (int k = 0; k < 4; k++) o[k] = f2bf(mu[k] + expf(ls[k])*ev[k]);
  *(u16x4*)&zo[(size_t)m*DECK + q*4] = o;
}

// ---------------- fused write: attn + canvas += (Fy^T @ w @ Fx)/gamma ----------------
__global__ __launch_bounds__(256) void write_fused(
    const float* __restrict__ wp, const float* __restrict__ w_b,
    const u16* __restrict__ hd, const float* __restrict__ attnW,
    const float* __restrict__ attn_b, float* __restrict__ canvas)
{
  const int b = blockIdx.x;
  const int tid = threadIdx.x;
  __shared__ float red[4][5];
  __shared__ float prm[5];
  __shared__ float inv[32];
  __shared__ float sW[1024];
  __shared__ __align__(16) float sF[32*132];
  __shared__ float sU[128*33];

  {
    float a0=0,a1=0,a2=0,a3=0,a4=0;
    const u16* h = hd + (size_t)b*DECK;
    for (int k = tid; k < HID; k += 256){
      const float hv = bf2f(h[k]);
      a0 += hv*attnW[k];
      a1 += hv*attnW[HID + k];
      a2 += hv*attnW[2*HID + k];
      a3 += hv*attnW[3*HID + k];
      a4 += hv*attnW[4*HID + k];
    }
    a0 = wsum(a0); a1 = wsum(a1); a2 = wsum(a2); a3 = wsum(a3); a4 = wsum(a4);
    if ((tid & 63) == 0){
      const int w = tid >> 6;
      red[w][0]=a0; red[w][1]=a1; red[w][2]=a2; red[w][3]=a3; red[w][4]=a4;
    }
  }
  for (int i = tid; i < 1024; i += 256)
    sW[i] = wp[(size_t)b*1024 + i] + wp[524288 + (size_t)b*1024 + i]
          + wp[2*524288 + (size_t)b*1024 + i] + wp[3*524288 + (size_t)b*1024 + i] + w_b[i];
  __syncthreads();
  if (tid < 5){
    const float p = red[0][tid]+red[1][tid]+red[2][tid]+red[3][tid] + attn_b[tid];
    float v;
    if (tid <= 1)      v = 64.5f*(p + 1.f);
    else if (tid == 2) v = 1.f/(2.f*expf(p));
    else if (tid == 3) v = (127.f/31.f)*expf(p);
    else               v = expf(p);
    prm[tid] = v;
  }
  __syncthreads();
  const float gx = prm[0], gy = prm[1], i2s = prm[2], dl = prm[3], gm = prm[4];

  auto genF = [&](float g0){
    for (int i = tid; i < 4096; i += 256){
      const int n = i >> 7, a = i & 127;
      const float mu = g0 + ((float)n - 16.5f)*dl;
      const float t = ((float)a - mu)*i2s;
      sF[n*132 + a] = expf(-t*t);
    }
    __syncthreads();
    if (tid < 32){
      float ssum = 0.f;
      for (int a = 0; a < 128; a++) ssum += sF[tid*132 + a];
      inv[tid] = 1.f/(ssum + 1e-9f);
    }
    __syncthreads();
    for (int i = tid; i < 4096; i += 256)
      sF[(i >> 7)*132 + (i & 127)] *= inv[i >> 7];
    __syncthreads();
  };

  genF(gy);   // Fy
  {
    const int Bg = tid & 31, mg = tid >> 5;
    float acc[4][4] = {};
    for (int n = 0; n < 32; n++){
      float fy[4], wv[4];
      #pragma unroll
      for (int i = 0; i < 4; i++) fy[i] = sF[n*132 + Bg + 32*i];
      #pragma unroll
      for (int j = 0; j < 4; j++) wv[j] = sW[n*32 + mg*4 + j];
      #pragma unroll
      for (int i = 0; i < 4; i++)
        #pragma unroll
        for (int j = 0; j < 4; j++) acc[i][j] += fy[i]*wv[j];
    }
    #pragma unroll
    for (int i = 0; i < 4; i++)
      #pragma unroll
      for (int j = 0; j < 4; j++)
        sU[(Bg + 32*i)*33 + mg*4 + j] = acc[i][j];
  }
  __syncthreads();
  genF(gx);   // Fx
  {
    const int Bg = tid & 31, ag = tid >> 5;
    float acc[64];
    #pragma unroll
    for (int k = 0; k < 64; k++) acc[k] = 0.f;
    for (int mm = 0; mm < 32; mm++){
      float u[4];
      #pragma unroll
      for (int i = 0; i < 4; i++) u[i] = sU[(Bg + 32*i)*33 + mm];
      f32x4 fx[4];
      #pragma unroll
      for (int k = 0; k < 4; k++) fx[k] = *(const f32x4*)&sF[mm*132 + ag*16 + k*4];
      #pragma unroll
      for (int i = 0; i < 4; i++)
        #pragma unroll
        for (int k = 0; k < 4; k++)
          #pragma unroll
          for (int cc = 0; cc < 4; cc++)
            acc[i*16 + k*4 + cc] += u[i]*fx[k][cc];
    }
    const float ig = 1.f/gm;
    #pragma unroll
    for (int i = 0; i < 4; i++){
      const int B_ = Bg + 32*i;
      #pragma unroll
      for (int k = 0; k < 4; k++){
        float* cp = &canvas[(size_t)b*ABF + B_*128 + ag*16 + k*4];
        f32x4 cv = *(const f32x4*)cp;
        #pragma unroll
        for (int cc = 0; cc < 4; cc++) cv[cc] += acc[i*16 + k*4 + cc]*ig;
        *(f32x4*)cp = cv;
      }
    }
  }
}

// ---------------- host ----------------
extern "C" void kernel_launch(void* const* d_in, const int* in_sizes, int n_in,
                              void* d_out, int out_size, void* d_ws, size_t ws_size,
                              hipStream_t stream)
{
  (void)in_sizes; (void)n_in; (void)out_size; (void)ws_size;
  const float* x      = (const float*)d_in[0];
  const float* eps    = (const float*)d_in[1];
  const float* encWih = (const float*)d_in[2];
  const float* encWhh = (const float*)d_in[3];
  const float* enc_b  = (const float*)d_in[4];
  const float* decWih = (const float*)d_in[5];
  const float* decWhh = (const float*)d_in[6];
  const float* dec_b  = (const float*)d_in[7];
  const float* muW    = (const float*)d_in[8];
  const float* mu_b   = (const float*)d_in[9];
  const float* sigW   = (const float*)d_in[10];
  const float* sig_b  = (const float*)d_in[11];
  const float* attnW  = (const float*)d_in[12];
  const float* attn_b = (const float*)d_in[13];
  const float* wW     = (const float*)d_in[14];
  const float* w_b    = (const float*)d_in[15];
  float* canvas = (float*)d_out;

  char* wsb = (char*)d_ws;
  size_t off = 0;
  auto alloc = [&](size_t bytes)->char*{
    char* p = wsb + off; off += (bytes + 255) & ~(size_t)255; return p;
  };
  // zeroed state region (contiguous, first): c_enc, c_dec, encA, decA
  float* c_enc = (float*)alloc(1048576*4);
  float* c_dec = (float*)alloc(1048576*4);
  u16*   encA  = (u16*)  alloc((size_t)BSZ*ENCK*2);   // [r | h_dec | h_enc]
  u16*   decA  = (u16*)  alloc((size_t)BSZ*DECK*2);   // [z | h_dec]
  const size_t state_bytes = off;
  // transients
  float* ps    = (float*)alloc(2304*4);
  float* pe    = (float*)alloc(256*4);
  float* h_tmp = (float*)alloc(1048576*4);
  float* g_buf = (float*)alloc((size_t)2*4194304*4);   // 2 split-K partials
  float* zbuf  = g_buf;                  // alias: lifetime disjoint from g use
  float* wbuf  = g_buf + 2097152;        // alias
  u16*   x_bf  = (u16*)  alloc((size_t)8388608*2);
  // bf16 weights (concatenated along K)
  u16* encW    = (u16*)alloc((size_t)G4*ENCK*2);   // [Wih | Whh]  (8192 x 6144)
  u16* decW    = (u16*)alloc((size_t)G4*DECK*2);   // [dWih | dWhh] (8192 x 2560)
  u16* muw_bf  = (u16*)alloc((size_t)1048576*2);
  u16* sigw_bf = (u16*)alloc((size_t)1048576*2);
  u16* ww_bf   = (u16*)alloc((size_t)2097152*2);

  // init
  zero_kernel<<<1024, 256, 0, stream>>>((float*)wsb, (int)(state_bytes/16));
  zero_kernel<<<2048, 256, 0, stream>>>(canvas, (ABF/4)*BSZ);
  cvt_kernel<<<2048, 256, 0, stream>>>(x,    x_bf,   8388608/4);
  cvt_strided_kernel<<<2048, 256, 0, stream>>>(encWih, encW, 8388608, 10, 1023, ENCK, 0);
  cvt_strided_kernel<<<2048, 256, 0, stream>>>(encWhh, encW, 4194304,  9,  511, ENCK, 4096);
  cvt_strided_kernel<<<1024, 256, 0, stream>>>(decWih, decW, 1048576,  7,  127, DECK, 0);
  cvt_strided_kernel<<<2048, 256, 0, stream>>>(decWhh, decW, 4194304,  9,  511, DECK, 512);
  cvt_kernel<<<512,  256, 0, stream>>>(muW,  muw_bf,  1048576/4);
  cvt_kernel<<<512,  256, 0, stream>>>(sigW, sigw_bf, 1048576/4);
  cvt_kernel<<<512,  256, 0, stream>>>(wW,   ww_bf,   2097152/4);

  Slices enc_sl = {};
  for (int k = 0; k < 2; k++)
    enc_sl.s[k] = { encA + 3072*k, encW + 3072*k, nullptr, g_buf + (size_t)k*4194304, ENCK, ENCK, 3072, 0 };

  Slices dec_sl = {};
  for (int k = 0; k < 2; k++)
    dec_sl.s[k] = { decA + 1280*k, decW + 1280*k, nullptr, g_buf + (size_t)k*4194304, DECK, DECK, 1280, 0 };

  Slices ms_sl = {}, w_sl = {};
  for (int k = 0; k < 4; k++){
    ms_sl.s[k] = { encA + 4096 + 512*k, muw_bf + 512*k, sigw_bf + 512*k, zbuf + (size_t)k*524288, ENCK, HID, 512, 0 };
    w_sl.s[k]  = { decA + 512  + 512*k, ww_bf  + 512*k, nullptr,         wbuf + (size_t)k*524288, DECK, HID, 512, 0 };
  }

  for (int t = 0; t < TSTEPS; t++){
    // read phase (attn from pre-update h_dec in decA, glimpse -> encA cols 0:2048)
    read_fused<<<512, 256, 0, stream>>>(x_bf, canvas, decA + 512, attnW, attn_b, encA);
    // encoder gates: phased 256x128 GEMM, split-K 2 over concat K=6144
    gemm_ph<<<256, 512, 0, stream>>>(enc_sl, G4);
    lstm_kernel<<<1024, 256, 0, stream>>>(g_buf, enc_b, c_enc, h_tmp, ps);
    sumexp_kernel<<<256, 256, 0, stream>>>(h_tmp, ps, pe);
    scale_kernel<<<1024, 256, 0, stream>>>(h_tmp, ps, pe, encA + 4096, ENCK, nullptr, 0);
    // mu | logsigma fused GEMM, split-K 4-way (n>=512 -> sig_W)
    gemm_bt<64,64><<<dim3(16,8,4), 256, 0, stream>>>(ms_sl, 512, 1024);
    z_kernel<<<256, 256, 0, stream>>>(zbuf, mu_b, sig_b, eps + (size_t)t*BSZ*ZD, decA);
    // decoder gates: phased GEMM, split-K 2 over concat K=2560
    gemm_ph<<<256, 512, 0, stream>>>(dec_sl, G4);
    lstm_kernel<<<1024, 256, 0, stream>>>(g_buf, dec_b, c_dec, h_tmp, ps);
    sumexp_kernel<<<256, 256, 0, stream>>>(h_tmp, ps, pe);
    scale_kernel<<<1024, 256, 0, stream>>>(h_tmp, ps, pe, decA + 512, DECK, encA + 2048, ENCK);
    // write phase (attn from updated h_dec)
    gemm_bt<64,64><<<dim3(16,8,4), 256, 0, stream>>>(w_sl, 0, 1024);
    write_fused<<<512, 256, 0, stream>>>(wbuf, w_b, decA + 512, attnW, attn_b, canvas);
  }
}